// Round 1
// baseline (239.234 us; speedup 1.0000x reference)
//
#include <hip/hip_runtime.h>

using i32x4 = __attribute__((ext_vector_type(4))) int;

#define AS3(p) ((__attribute__((address_space(3))) void*)(p))
#define AS1(p) ((const __attribute__((address_space(1))) void*)(p))

constexpr int M = 8192;
constexpr int N = 4096;
constexpr int K = 4096;

// ---------------- Pass 1a: pack x (int32 -> int8), layout preserved [M][K] ----------------
__global__ void pack_a_kernel(const int4* __restrict__ x, unsigned* __restrict__ a8, int nUnits) {
    int stride = gridDim.x * blockDim.x;
    for (int u = blockIdx.x * blockDim.x + threadIdx.x; u < nUnits; u += stride) {
        int4 v = x[u];  // 4 consecutive k-values
        a8[u] = (v.x & 255) | ((v.y & 255) << 8) | ((v.z & 255) << 16) | (v.w << 24);
    }
}

// ---------------- Pass 1b: pack + transpose W: [K][N] int32 -> [N][K] int8 ----------------
// 64x64 tile per block, 256 threads, LDS-staged transpose.
__global__ void pack_wT_kernel(const int* __restrict__ w, char* __restrict__ b8t) {
    __shared__ __align__(16) char T[64][80];   // [n][k], padded stride 80 (16-aligned)
    const int n0 = blockIdx.x * 64;
    const int k0 = blockIdx.y * 64;
    const int tid = threadIdx.x;

    // stage: each thread loads 4 dwordx4 (4 consecutive n at one k), scatters bytes transposed
    #pragma unroll
    for (int i = 0; i < 4; i++) {
        int u = tid + i * 256;         // 0..1023
        int r = u >> 4;                // k row 0..63
        int c = u & 15;                // n group (4 each)
        int4 v = *(const int4*)&w[(size_t)(k0 + r) * N + n0 + 4 * c];
        T[4 * c + 0][r] = (char)v.x;
        T[4 * c + 1][r] = (char)v.y;
        T[4 * c + 2][r] = (char)v.z;
        T[4 * c + 3][r] = (char)v.w;
    }
    __syncthreads();

    // write out: thread -> (n = tid/4, 16B k-chunk q = tid%4); 4 threads cover one 64B n-row
    const int n = tid >> 2;
    const int q = tid & 3;
    int4 val = *(const int4*)&T[n][16 * q];
    *(int4*)&b8t[(size_t)(n0 + n) * K + k0 + 16 * q] = val;
}

// ---------------- Pass 2: i8 GEMM, 256x256 tile, BK=64, 8 waves ----------------
__global__ __launch_bounds__(512, 2) void gemm_i8_kernel(
    const char* __restrict__ a8, const char* __restrict__ b8t,
    const int* __restrict__ bias, const float* __restrict__ scales,
    float* __restrict__ out)
{
    __shared__ __align__(16) char As[2][256 * 64];   // 16 KB each
    __shared__ __align__(16) char Bs[2][256 * 64];

    const int tid  = threadIdx.x;
    const int lane = tid & 63;
    const int wid  = tid >> 6;
    const int wr   = wid >> 2;   // 0..1  -> 128-row band
    const int wc   = wid & 3;    // 0..3  -> 64-col band

    // XCD-aware swizzle (gridDim.x = 512, divisible by 8)
    const int bid = blockIdx.x;
    const int cpx = gridDim.x >> 3;
    const int sw  = (bid & 7) * cpx + (bid >> 3);
    const int tm  = sw >> 4;     // 32 M-tiles
    const int tn  = sw & 15;     // 16 N-tiles
    const size_t brow = (size_t)tm * 256;
    const size_t bcol = (size_t)tn * 256;

    // staging addresses: thread covers (row = tid/4 [+128], 16B chunk = tid%4)
    const int srow = tid >> 2;
    const int sch  = (tid & 3) << 4;
    const char* aG = a8  + (brow + srow) * (size_t)K + sch;
    const char* bG = b8t + (bcol + srow) * (size_t)K + sch;
    const int ldsOff = wid * 1024;   // wave-uniform LDS base (lane*16 added by HW)

    i32x4 acc[8][4];
    #pragma unroll
    for (int m = 0; m < 8; m++)
        #pragma unroll
        for (int n = 0; n < 4; n++)
            #pragma unroll
            for (int r = 0; r < 4; r++)
                acc[m][n][r] = 0;

    auto stage = [&](int buf, int kt) {
        const char* ak = aG + kt * 64;
        const char* bk = bG + kt * 64;
        __builtin_amdgcn_global_load_lds(AS1(ak),                    AS3(&As[buf][ldsOff]),        16, 0, 0);
        __builtin_amdgcn_global_load_lds(AS1(ak + (size_t)128 * K),  AS3(&As[buf][8192 + ldsOff]), 16, 0, 0);
        __builtin_amdgcn_global_load_lds(AS1(bk),                    AS3(&Bs[buf][ldsOff]),        16, 0, 0);
        __builtin_amdgcn_global_load_lds(AS1(bk + (size_t)128 * K),  AS3(&Bs[buf][8192 + ldsOff]), 16, 0, 0);
    };

    stage(0, 0);
    __syncthreads();   // compiler drains vmcnt before s_barrier

    // fragment read offset: lane -> row (lane&15), k-chunk (lane>>4)*16.
    // 16 rows x 64B = contiguous 1KB per fragment group -> conflict-free, no swizzle needed.
    const int rowoff = (lane & 15) * 64 + (lane >> 4) * 16;

    int cur = 0;
    for (int kt = 0; kt < K / 64; kt++) {
        if (kt + 1 < K / 64) stage(cur ^ 1, kt + 1);

        const char* Ab = &As[cur][wr * 8192];
        const char* Bb = &Bs[cur][wc * 4096];
        i32x4 bfr[4];
        #pragma unroll
        for (int n = 0; n < 4; n++)
            bfr[n] = *(const i32x4*)(Bb + n * 1024 + rowoff);
        #pragma unroll
        for (int m = 0; m < 8; m++) {
            i32x4 afr = *(const i32x4*)(Ab + m * 1024 + rowoff);
            #pragma unroll
            for (int n = 0; n < 4; n++)
                acc[m][n] = __builtin_amdgcn_mfma_i32_16x16x64_i8(afr, bfr[n], acc[m][n], 0, 0, 0);
        }
        __syncthreads();   // drains vmcnt(0) (stage visible) + frees cur buffer for next stage
        cur ^= 1;
    }

    // epilogue: D col = lane&15, row = (lane>>4)*4 + reg  (dtype-independent C/D layout)
    #pragma unroll
    for (int n = 0; n < 4; n++) {
        const int col = (int)bcol + wc * 64 + n * 16 + (lane & 15);
        const int bv  = bias[col];
        const float sv = scales[col];
        #pragma unroll
        for (int m = 0; m < 8; m++) {
            const size_t row0 = brow + wr * 128 + m * 16 + ((lane >> 4) << 2);
            float* o = out + row0 * (size_t)N + col;
            #pragma unroll
            for (int r = 0; r < 4; r++)
                o[(size_t)r * N] = (float)(acc[m][n][r] + bv) * sv;
        }
    }
}

extern "C" void kernel_launch(void* const* d_in, const int* in_sizes, int n_in,
                              void* d_out, int out_size, void* d_ws, size_t ws_size,
                              hipStream_t stream) {
    const int*   x      = (const int*)d_in[0];
    const int*   w      = (const int*)d_in[1];
    const int*   bias   = (const int*)d_in[2];
    const float* scales = (const float*)d_in[3];
    float* out = (float*)d_out;

    char* a8  = (char*)d_ws;                       // M*K   = 32 MB
    char* b8t = a8 + (size_t)M * K;                // N*K   = 16 MB   (total 50.3 MB)

    pack_a_kernel<<<2048, 256, 0, stream>>>((const int4*)x, (unsigned*)a8, M * K / 4);

    dim3 gt(N / 64, K / 64);
    pack_wT_kernel<<<gt, 256, 0, stream>>>(w, b8t);

    gemm_i8_kernel<<<(M / 256) * (N / 256), 512, 0, stream>>>(a8, b8t, bias, scales, out);
}

// Round 2
// 225.453 us; speedup vs baseline: 1.0611x; 1.0611x over previous
//
#include <hip/hip_runtime.h>

using i32x4 = __attribute__((ext_vector_type(4))) int;

#define AS3(p) ((__attribute__((address_space(3))) void*)(p))
#define AS1(p) ((const __attribute__((address_space(1))) void*)(p))

constexpr int M = 8192;
constexpr int N = 4096;
constexpr int K = 4096;
constexpr int BK = 128;          // i8 K-tile: 128 B/row (byte-identical to bf16 BK=64 template)
constexpr int NT = K / BK;       // 32

// ---------------- Pass 1a: pack x (int32 -> int8), layout preserved [M][K] ----------------
__global__ void pack_a_kernel(const int4* __restrict__ x, unsigned* __restrict__ a8, int nUnits) {
    int stride = gridDim.x * blockDim.x;
    for (int u = blockIdx.x * blockDim.x + threadIdx.x; u < nUnits; u += stride) {
        int4 v = x[u];
        a8[u] = (v.x & 255) | ((v.y & 255) << 8) | ((v.z & 255) << 16) | (v.w << 24);
    }
}

// ---------------- Pass 1b: pack + transpose W: [K][N] int32 -> [N][K] int8 ----------------
__global__ void pack_wT_kernel(const int* __restrict__ w, char* __restrict__ b8t) {
    __shared__ __align__(16) char T[64][80];
    const int n0 = blockIdx.x * 64;
    const int k0 = blockIdx.y * 64;
    const int tid = threadIdx.x;

    #pragma unroll
    for (int i = 0; i < 4; i++) {
        int u = tid + i * 256;
        int r = u >> 4;
        int c = u & 15;
        int4 v = *(const int4*)&w[(size_t)(k0 + r) * N + n0 + 4 * c];
        T[4 * c + 0][r] = (char)v.x;
        T[4 * c + 1][r] = (char)v.y;
        T[4 * c + 2][r] = (char)v.z;
        T[4 * c + 3][r] = (char)v.w;
    }
    __syncthreads();

    const int n = tid >> 2;
    const int q = tid & 3;
    int4 val = *(const int4*)&T[n][16 * q];
    *(int4*)&b8t[(size_t)(n0 + n) * K + k0 + 16 * q] = val;
}

// ---------------- Pass 2: i8 GEMM, 256x256 tile, BK=128, 8 waves, 8-phase-style schedule ----------------
// LDS layout per buffer: [256 rows][128 B], XOR-swizzled: LDS slot (row, c) holds global
// 16B-chunk (c ^ (row&7)) of that row. Staging pre-swizzles the GLOBAL source (rule #21:
// global_load_lds writes linearly); ds_read applies the same XOR. Fragment reads are then
// bank-conflict-free (each 4-bank group hit exactly 2x per 16-lane quarter-wave).
__global__ __launch_bounds__(512, 1) void gemm_i8_kernel(
    const char* __restrict__ a8, const char* __restrict__ b8t,
    const int* __restrict__ bias, const float* __restrict__ scales,
    float* __restrict__ out)
{
    __shared__ __align__(16) char As[2][256 * BK];   // 32 KB each
    __shared__ __align__(16) char Bs[2][256 * BK];   // total 128 KB -> 1 block/CU

    const int tid  = threadIdx.x;
    const int lane = tid & 63;
    const int wid  = tid >> 6;
    const int wr   = wid >> 2;   // 0..1 -> 128-row band
    const int wc   = wid & 3;    // 0..3 -> 64-col band

    // XCD-aware swizzle (512 blocks, %8 == 0 -> bijective)
    const int bid = blockIdx.x;
    const int cpx = gridDim.x >> 3;
    const int sw  = (bid & 7) * cpx + (bid >> 3);
    const int tm  = sw >> 4;
    const int tn  = sw & 15;
    const size_t brow = (size_t)tm * 256;
    const size_t bcol = (size_t)tn * 256;

    // Staging: 8 loads/thread per K-tile (4 A-slabs + 4 B-slabs of 64 rows each).
    // Thread covers row slab tid>>3 (0..63), 16B chunk (tid&7) PRE-SWIZZLED in the source.
    const int srow = tid >> 3;
    const int schS = ((tid & 7) ^ (srow & 7)) << 4;
    const char* aG = a8  + (brow + srow) * (size_t)K + schS;
    const char* bG = b8t + (bcol + srow) * (size_t)K + schS;
    const int ldsW = wid * 1024;   // wave-uniform dest base; HW adds lane*16

    i32x4 acc[8][4];
    #pragma unroll
    for (int m = 0; m < 8; m++)
        #pragma unroll
        for (int n = 0; n < 4; n++)
            #pragma unroll
            for (int r = 0; r < 4; r++)
                acc[m][n][r] = 0;

    auto stageAll = [&](int b, int kt) {
        const char* a  = aG + (size_t)kt * BK;
        const char* bb = bG + (size_t)kt * BK;
        char* Ad = &As[b][0] + ldsW;
        char* Bd = &Bs[b][0] + ldsW;
        __builtin_amdgcn_global_load_lds(AS1(a),                  AS3(Ad),         16, 0, 0);
        __builtin_amdgcn_global_load_lds(AS1(a  + (size_t) 64*K), AS3(Ad +  8192), 16, 0, 0);
        __builtin_amdgcn_global_load_lds(AS1(a  + (size_t)128*K), AS3(Ad + 16384), 16, 0, 0);
        __builtin_amdgcn_global_load_lds(AS1(a  + (size_t)192*K), AS3(Ad + 24576), 16, 0, 0);
        __builtin_amdgcn_global_load_lds(AS1(bb),                 AS3(Bd),         16, 0, 0);
        __builtin_amdgcn_global_load_lds(AS1(bb + (size_t) 64*K), AS3(Bd +  8192), 16, 0, 0);
        __builtin_amdgcn_global_load_lds(AS1(bb + (size_t)128*K), AS3(Bd + 16384), 16, 0, 0);
        __builtin_amdgcn_global_load_lds(AS1(bb + (size_t)192*K), AS3(Bd + 24576), 16, 0, 0);
    };

    // Fragment read addressing: row = band + m*16 + (lane&15); chunk c = kk*4 + (lane>>4),
    // swizzled c' = c ^ (lane&7)  (row&7 == lane&7 since all band offsets are %8==0).
    const int frow = lane & 15;
    const int c0 = ((lane >> 4) ^ (lane & 7)) << 4;  // kk=0 swizzled chunk byte offset
    const int c1 = c0 ^ 64;                          // kk=1 (chunk XOR 4 -> byte XOR 64)
    const int raBase = wr * 16384 + frow * 128;
    const int rbBase = wc * 8192  + frow * 128;

    stageAll(0, 0);
    asm volatile("s_waitcnt vmcnt(0)" ::: "memory");
    __builtin_amdgcn_s_barrier();

    int cur = 0;
    for (int kt = 0; kt < NT; ++kt) {
        const char* Ab = &As[cur][0] + raBase;
        const char* Bb = &Bs[cur][0] + rbBase;

        i32x4 bfr[4][2];   // all B frags for this K-tile, live across phases

        // ---- phase 0: stage next tile (8 loads, drained at tile boundary) + B-all + A m0/m1 ----
        if (kt + 1 < NT) stageAll(cur ^ 1, kt + 1);
        #pragma unroll
        for (int n = 0; n < 4; ++n) {
            bfr[n][0] = *(const i32x4*)(Bb + n * 2048 + c0);
            bfr[n][1] = *(const i32x4*)(Bb + n * 2048 + c1);
        }
        {
            i32x4 a00 = *(const i32x4*)(Ab + 0 * 2048 + c0);
            i32x4 a01 = *(const i32x4*)(Ab + 0 * 2048 + c1);
            i32x4 a10 = *(const i32x4*)(Ab + 1 * 2048 + c0);
            i32x4 a11 = *(const i32x4*)(Ab + 1 * 2048 + c1);
            __builtin_amdgcn_s_barrier();
            asm volatile("s_waitcnt lgkmcnt(0)" ::: "memory");
            __builtin_amdgcn_sched_barrier(0);
            __builtin_amdgcn_s_setprio(1);
            #pragma unroll
            for (int n = 0; n < 4; ++n) {
                acc[0][n] = __builtin_amdgcn_mfma_i32_16x16x64_i8(a00, bfr[n][0], acc[0][n], 0, 0, 0);
                acc[0][n] = __builtin_amdgcn_mfma_i32_16x16x64_i8(a01, bfr[n][1], acc[0][n], 0, 0, 0);
                acc[1][n] = __builtin_amdgcn_mfma_i32_16x16x64_i8(a10, bfr[n][0], acc[1][n], 0, 0, 0);
                acc[1][n] = __builtin_amdgcn_mfma_i32_16x16x64_i8(a11, bfr[n][1], acc[1][n], 0, 0, 0);
            }
            __builtin_amdgcn_s_setprio(0);
            __builtin_amdgcn_sched_barrier(0);
            __builtin_amdgcn_s_barrier();
        }

        // ---- phases 1..3: A m-pair each; tile-boundary drain folded into phase 3 ----
        #pragma unroll
        for (int p = 1; p < 4; ++p) {
            i32x4 a00 = *(const i32x4*)(Ab + (2 * p)     * 2048 + c0);
            i32x4 a01 = *(const i32x4*)(Ab + (2 * p)     * 2048 + c1);
            i32x4 a10 = *(const i32x4*)(Ab + (2 * p + 1) * 2048 + c0);
            i32x4 a11 = *(const i32x4*)(Ab + (2 * p + 1) * 2048 + c1);
            __builtin_amdgcn_s_barrier();
            asm volatile("s_waitcnt lgkmcnt(0)" ::: "memory");
            __builtin_amdgcn_sched_barrier(0);
            __builtin_amdgcn_s_setprio(1);
            #pragma unroll
            for (int n = 0; n < 4; ++n) {
                acc[2 * p][n]     = __builtin_amdgcn_mfma_i32_16x16x64_i8(a00, bfr[n][0], acc[2 * p][n], 0, 0, 0);
                acc[2 * p][n]     = __builtin_amdgcn_mfma_i32_16x16x64_i8(a01, bfr[n][1], acc[2 * p][n], 0, 0, 0);
                acc[2 * p + 1][n] = __builtin_amdgcn_mfma_i32_16x16x64_i8(a10, bfr[n][0], acc[2 * p + 1][n], 0, 0, 0);
                acc[2 * p + 1][n] = __builtin_amdgcn_mfma_i32_16x16x64_i8(a11, bfr[n][1], acc[2 * p + 1][n], 0, 0, 0);
            }
            __builtin_amdgcn_s_setprio(0);
            __builtin_amdgcn_sched_barrier(0);
            if (p == 3) {
                // loads for tile kt+1 were issued ~3 full MFMA phases ago -> near-free drain
                asm volatile("s_waitcnt vmcnt(0)" ::: "memory");
            }
            __builtin_amdgcn_s_barrier();
        }
        cur ^= 1;
    }

    // epilogue: D col = lane&15 (N-dim), row = (lane>>4)*4 + reg (verified absmax 0 in r1)
    #pragma unroll
    for (int n = 0; n < 4; ++n) {
        const int col = (int)bcol + wc * 64 + n * 16 + (lane & 15);
        const int bv  = bias[col];
        const float sv = scales[col];
        #pragma unroll
        for (int m = 0; m < 8; ++m) {
            const size_t row0 = brow + wr * 128 + m * 16 + ((lane >> 4) << 2);
            float* o = out + row0 * (size_t)N + col;
            #pragma unroll
            for (int r = 0; r < 4; ++r)
                o[(size_t)r * N] = (float)(acc[m][n][r] + bv) * sv;
        }
    }
}

extern "C" void kernel_launch(void* const* d_in, const int* in_sizes, int n_in,
                              void* d_out, int out_size, void* d_ws, size_t ws_size,
                              hipStream_t stream) {
    const int*   x      = (const int*)d_in[0];
    const int*   w      = (const int*)d_in[1];
    const int*   bias   = (const int*)d_in[2];
    const float* scales = (const float*)d_in[3];
    float* out = (float*)d_out;

    char* a8  = (char*)d_ws;                       // M*K = 32 MB
    char* b8t = a8 + (size_t)M * K;                // N*K = 16 MB

    pack_a_kernel<<<2048, 256, 0, stream>>>((const int4*)x, (unsigned*)a8, M * K / 4);

    dim3 gt(N / 64, K / 64);
    pack_wT_kernel<<<gt, 256, 0, stream>>>(w, b8t);

    gemm_i8_kernel<<<(M / 256) * (N / 256), 512, 0, stream>>>(a8, b8t, bias, scales, out);
}

// Round 3
// 206.402 us; speedup vs baseline: 1.1591x; 1.0923x over previous
//
#include <hip/hip_runtime.h>

using i32x4 = __attribute__((ext_vector_type(4))) int;

#define AS3(p) ((__attribute__((address_space(3))) void*)(p))
#define AS1(p) ((const __attribute__((address_space(1))) void*)(p))

constexpr int M = 8192;
constexpr int N = 4096;
constexpr int K = 4096;
constexpr int BK = 64;           // 64 B/row per K-tile
constexpr int NT = K / BK;       // 64 K-tiles
constexpr int NBUF = 4;          // 4-deep LDS ring -> prefetch 3 tiles ahead

// ---------------- Pass 1a: pack x (int32 -> int8), layout preserved [M][K] ----------------
__global__ void pack_a_kernel(const int4* __restrict__ x, unsigned* __restrict__ a8, int nUnits) {
    int stride = gridDim.x * blockDim.x;
    for (int u = blockIdx.x * blockDim.x + threadIdx.x; u < nUnits; u += stride) {
        int4 v = x[u];
        a8[u] = (v.x & 255) | ((v.y & 255) << 8) | ((v.z & 255) << 16) | (v.w << 24);
    }
}

// ---------------- Pass 1b: pack + transpose W: [K][N] int32 -> [N][K] int8 ----------------
__global__ void pack_wT_kernel(const int* __restrict__ w, char* __restrict__ b8t) {
    __shared__ __align__(16) char T[64][80];
    const int n0 = blockIdx.x * 64;
    const int k0 = blockIdx.y * 64;
    const int tid = threadIdx.x;

    #pragma unroll
    for (int i = 0; i < 4; i++) {
        int u = tid + i * 256;
        int r = u >> 4;
        int c = u & 15;
        int4 v = *(const int4*)&w[(size_t)(k0 + r) * N + n0 + 4 * c];
        T[4 * c + 0][r] = (char)v.x;
        T[4 * c + 1][r] = (char)v.y;
        T[4 * c + 2][r] = (char)v.z;
        T[4 * c + 3][r] = (char)v.w;
    }
    __syncthreads();

    const int n = tid >> 2;
    const int q = tid & 3;
    int4 val = *(const int4*)&T[n][16 * q];
    *(int4*)&b8t[(size_t)(n0 + n) * K + k0 + 16 * q] = val;
}

// ---------------- Pass 2: i8 GEMM, 256x256 tile, BK=64, 4-buffer 3-deep pipeline ----------------
// LDS per buffer: A 256x64B (16 KB) + B 256x64B (16 KB). 4 buffers = 128 KB.
// Chunk swizzle: slot (row, c) holds global chunk c ^ ((row>>1)&3); applied on BOTH sides
// (pre-swizzled global staging source + swizzled ds_read) -> residual 2-way aliasing = free.
// Steady state: 12 global_load_lds in flight; end-of-tile waits vmcnt(8) (counted, never 0).
__global__ __launch_bounds__(512, 1) void gemm_i8_kernel(
    const char* __restrict__ a8, const char* __restrict__ b8t,
    const int* __restrict__ bias, const float* __restrict__ scales,
    float* __restrict__ out)
{
    __shared__ __align__(16) char As[NBUF][256 * BK];   // 16 KB each
    __shared__ __align__(16) char Bs[NBUF][256 * BK];

    const int tid  = threadIdx.x;
    const int lane = tid & 63;
    const int wid  = tid >> 6;
    const int wr   = wid >> 2;   // 0..1 -> 128-row band
    const int wc   = wid & 3;    // 0..3 -> 64-col band

    // XCD-aware remap: each XCD chunk covers an 8x8 (tm,tn) square -> per-K-window L2
    // working set 256 KB, panel traffic 16 MB/XCD.
    const int bid = blockIdx.x;
    const int xcd = bid & 7;
    const int l   = bid >> 3;
    const int tm  = (xcd >> 1) * 8 + (l >> 3);   // 0..31
    const int tn  = (xcd & 1) * 8 + (l & 7);     // 0..15
    const size_t brow = (size_t)tm * 256;
    const size_t bcol = (size_t)tn * 256;

    // Staging: 4 loads/thread/tile (2 A-halves + 2 B-halves of 128 rows each).
    // Thread t -> row t>>2 (0..127), source chunk (t&3) ^ ((row>>1)&3)  [pre-swizzle].
    const int srow = tid >> 2;
    const int schS = ((tid & 3) ^ ((tid >> 3) & 3)) << 4;
    const char* aG = a8  + (brow + srow) * (size_t)K + schS;
    const char* bG = b8t + (bcol + srow) * (size_t)K + schS;
    const int ldsW = wid * 1024;   // wave-uniform dest; HW adds lane*16

    i32x4 acc[8][4];
    #pragma unroll
    for (int m = 0; m < 8; m++)
        #pragma unroll
        for (int n = 0; n < 4; n++)
            #pragma unroll
            for (int r = 0; r < 4; r++)
                acc[m][n][r] = 0;

    auto stage = [&](int slot, int kt) {
        const char* a = aG + (size_t)kt * BK;
        const char* b = bG + (size_t)kt * BK;
        char* Ad = &As[slot][0] + ldsW;
        char* Bd = &Bs[slot][0] + ldsW;
        __builtin_amdgcn_global_load_lds(AS1(a),                  AS3(Ad),        16, 0, 0);
        __builtin_amdgcn_global_load_lds(AS1(a + (size_t)128*K),  AS3(Ad + 8192), 16, 0, 0);
        __builtin_amdgcn_global_load_lds(AS1(b),                  AS3(Bd),        16, 0, 0);
        __builtin_amdgcn_global_load_lds(AS1(b + (size_t)128*K),  AS3(Bd + 8192), 16, 0, 0);
    };

    // Fragment read: row = band + m*16 + (lane&15); chunk c = lane>>4, swizzled by
    // ((row>>1)&3) = (((lane&15)>>1)&3) since band/m offsets are multiples of 16.
    const int frow  = lane & 15;
    const int c0sw  = ((lane >> 4) ^ ((frow >> 1) & 3)) << 4;
    const int raOff = wr * 8192 + frow * 64 + c0sw;
    const int rbOff = wc * 4096 + frow * 64 + c0sw;

    // Prologue: fill 3 buffers, wait only the first.
    stage(0, 0);
    stage(1, 1);
    stage(2, 2);
    asm volatile("s_waitcnt vmcnt(8)" ::: "memory");
    __builtin_amdgcn_s_barrier();

    #pragma unroll 4
    for (int t = 0; t < NT; ++t) {
        const int slot = t & 3;
        if (t + 3 < NT) stage((t + 3) & 3, t + 3);

        const char* Ab = &As[slot][0] + raOff;
        const char* Bb = &Bs[slot][0] + rbOff;

        i32x4 bfr[4], afr[8];
        #pragma unroll
        for (int n = 0; n < 4; ++n)
            bfr[n] = *(const i32x4*)(Bb + n * 1024);
        #pragma unroll
        for (int m = 0; m < 8; ++m)
            afr[m] = *(const i32x4*)(Ab + m * 1024);

        __builtin_amdgcn_s_barrier();           // phase-align the 8 waves

        asm volatile("s_waitcnt lgkmcnt(4)" ::: "memory");   // B(4)+A0-3(4) done
        __builtin_amdgcn_sched_barrier(0);
        __builtin_amdgcn_s_setprio(1);
        #pragma unroll
        for (int m = 0; m < 4; ++m)
            #pragma unroll
            for (int n = 0; n < 4; ++n)
                acc[m][n] = __builtin_amdgcn_mfma_i32_16x16x64_i8(afr[m], bfr[n], acc[m][n], 0, 0, 0);
        __builtin_amdgcn_s_setprio(0);
        __builtin_amdgcn_sched_barrier(0);

        asm volatile("s_waitcnt lgkmcnt(0)" ::: "memory");   // A4-7 done
        __builtin_amdgcn_sched_barrier(0);
        __builtin_amdgcn_s_setprio(1);
        #pragma unroll
        for (int m = 4; m < 8; ++m)
            #pragma unroll
            for (int n = 0; n < 4; ++n)
                acc[m][n] = __builtin_amdgcn_mfma_i32_16x16x64_i8(afr[m], bfr[n], acc[m][n], 0, 0, 0);
        __builtin_amdgcn_s_setprio(0);
        __builtin_amdgcn_sched_barrier(0);

        // counted drain: stages t+1..t+3 outstanding (12); wait oldest 4 -> buf t+1 ready
        if (t <= NT - 4) asm volatile("s_waitcnt vmcnt(8)" ::: "memory");
        else             asm volatile("s_waitcnt vmcnt(0)" ::: "memory");
        __builtin_amdgcn_s_barrier();
    }

    // epilogue: D col = lane&15 (N-dim), row = (lane>>4)*4 + reg (absmax 0 in r1/r2)
    #pragma unroll
    for (int n = 0; n < 4; ++n) {
        const int col = (int)bcol + wc * 64 + n * 16 + (lane & 15);
        const int bv  = bias[col];
        const float sv = scales[col];
        #pragma unroll
        for (int m = 0; m < 8; ++m) {
            const size_t row0 = brow + wr * 128 + m * 16 + ((lane >> 4) << 2);
            float* o = out + row0 * (size_t)N + col;
            #pragma unroll
            for (int r = 0; r < 4; ++r)
                o[(size_t)r * N] = (float)(acc[m][n][r] + bv) * sv;
        }
    }
}

extern "C" void kernel_launch(void* const* d_in, const int* in_sizes, int n_in,
                              void* d_out, int out_size, void* d_ws, size_t ws_size,
                              hipStream_t stream) {
    const int*   x      = (const int*)d_in[0];
    const int*   w      = (const int*)d_in[1];
    const int*   bias   = (const int*)d_in[2];
    const float* scales = (const float*)d_in[3];
    float* out = (float*)d_out;

    char* a8  = (char*)d_ws;                       // M*K = 32 MB
    char* b8t = a8 + (size_t)M * K;                // N*K = 16 MB

    pack_a_kernel<<<2048, 256, 0, stream>>>((const int4*)x, (unsigned*)a8, M * K / 4);

    dim3 gt(N / 64, K / 64);
    pack_wT_kernel<<<gt, 256, 0, stream>>>(w, b8t);

    gemm_i8_kernel<<<(M / 256) * (N / 256), 512, 0, stream>>>(a8, b8t, bias, scales, out);
}